// Round 1
// baseline (83.969 us; speedup 1.0000x reference)
//
#include <hip/hip_runtime.h>

#define NCLS 21
#define HW (512 * 512)          // pixels per plane (2^18)
#define NB 16                   // batch
#define NPIX (NB * HW)          // 4,194,304 pixels
#define NVEC (NPIX / 4)         // 1,048,576 float4 groups

// Phase 1: per-pixel argmax over 21 classes + LDS histograms -> global counters.
// cnt layout: [0..20] inter, [21..41] cp (pred counts), [42..62] cg (gt counts)
__global__ void __launch_bounds__(256) iou_hist_kernel(
    const float* __restrict__ pred, const int* __restrict__ gt,
    unsigned int* __restrict__ cnt) {
    __shared__ unsigned int h[3 * NCLS];
    for (int i = threadIdx.x; i < 3 * NCLS; i += blockDim.x) h[i] = 0u;
    __syncthreads();

    const int nthreads = gridDim.x * blockDim.x;
    for (int v = blockIdx.x * blockDim.x + threadIdx.x; v < NVEC; v += nthreads) {
        const int p0 = v << 2;            // first pixel of this 4-group
        const int b  = p0 >> 18;          // p0 / HW
        const int hw = p0 & (HW - 1);     // p0 % HW (multiple of 4)
        const float4* base =
            (const float4*)(pred + (size_t)(b * NCLS) * HW + hw);

        float4 m = base[0];
        int ix = 0, iy = 0, iz = 0, iw = 0;
#pragma unroll
        for (int c = 1; c < NCLS; ++c) {
            float4 x = base[(size_t)c * (HW / 4)];
            if (x.x > m.x) { m.x = x.x; ix = c; }
            if (x.y > m.y) { m.y = x.y; iy = c; }
            if (x.z > m.z) { m.z = x.z; iz = c; }
            if (x.w > m.w) { m.w = x.w; iw = c; }
        }

        const int4 g = *(const int4*)(gt + p0);

        atomicAdd(&h[NCLS + ix], 1u);
        atomicAdd(&h[NCLS + iy], 1u);
        atomicAdd(&h[NCLS + iz], 1u);
        atomicAdd(&h[NCLS + iw], 1u);
        atomicAdd(&h[2 * NCLS + g.x], 1u);
        atomicAdd(&h[2 * NCLS + g.y], 1u);
        atomicAdd(&h[2 * NCLS + g.z], 1u);
        atomicAdd(&h[2 * NCLS + g.w], 1u);
        if (ix == g.x) atomicAdd(&h[ix], 1u);
        if (iy == g.y) atomicAdd(&h[iy], 1u);
        if (iz == g.z) atomicAdd(&h[iz], 1u);
        if (iw == g.w) atomicAdd(&h[iw], 1u);
    }

    __syncthreads();
    for (int i = threadIdx.x; i < 3 * NCLS; i += blockDim.x) {
        unsigned int val = h[i];
        if (val) atomicAdd(&cnt[i], val);   // device-scope by default (G12)
    }
}

// Phase 2: one wave computes per-class IoU and the mean.
__global__ void iou_final_kernel(const unsigned int* __restrict__ cnt,
                                 float* __restrict__ out) {
    const int lane = threadIdx.x;
    float iou = 0.0f;
    if (lane < NCLS) {
        const float inter = (float)cnt[lane];
        const float cp    = (float)cnt[NCLS + lane];
        const float cg    = (float)cnt[2 * NCLS + lane];
        const float uni   = cp + cg - inter;
        iou = (inter > 0.0f) ? inter / (uni > 0.0f ? uni : 1.0f) : 0.0f;
    }
#pragma unroll
    for (int off = 32; off >= 1; off >>= 1)
        iou += __shfl_down(iou, off, 64);
    if (lane == 0) out[0] = iou / (float)NCLS;
}

extern "C" void kernel_launch(void* const* d_in, const int* in_sizes, int n_in,
                              void* d_out, int out_size, void* d_ws, size_t ws_size,
                              hipStream_t stream) {
    const float* pred = (const float*)d_in[0];
    const int*   gt   = (const int*)d_in[1];
    float*       out  = (float*)d_out;
    unsigned int* cnt = (unsigned int*)d_ws;

    // d_ws is poisoned once (0xAA) and never re-poisoned: zero it every call.
    hipMemsetAsync(cnt, 0, 3 * NCLS * sizeof(unsigned int), stream);

    iou_hist_kernel<<<2048, 256, 0, stream>>>(pred, gt, cnt);
    iou_final_kernel<<<1, 64, 0, stream>>>(cnt, out);
}